// Round 10
// baseline (404.665 us; speedup 1.0000x reference)
//
#include <hip/hip_runtime.h>
#include <cmath>
#include <stdint.h>

typedef unsigned short u16;
typedef __attribute__((ext_vector_type(8))) short short8;
typedef __attribute__((ext_vector_type(4))) float f32x4;
typedef __attribute__((ext_vector_type(4))) unsigned int u32x4;

#define HID 768
#define FF  3072
#define SEQ 2048
#define NHEAD 12
#define NROWS 8192   // B*S

__device__ __forceinline__ float bf2f(u16 u){ return __uint_as_float(((unsigned)u)<<16); }
__device__ __forceinline__ u16 f2bf(float f){
  unsigned x = __float_as_uint(f);
  x += 0x7fffu + ((x>>16)&1u);
  return (u16)(x>>16);
}
__device__ __forceinline__ unsigned cvtpk(float a, float b){   // lo=bf16(a), hi=bf16(b)
  unsigned r;
  asm("v_cvt_pk_bf16_f32 %0, %1, %2" : "=v"(r) : "v"(a), "v"(b));
  return r;
}
__device__ __forceinline__ void gload16(const void* g, void* l){
  __builtin_amdgcn_global_load_lds((const __attribute__((address_space(1))) unsigned*)g,
                                   (__attribute__((address_space(3))) unsigned*)l, 16, 0, 0);
}

// ---------------- weight convert + transpose: in fp32 [K][N] -> out bf16 [N][K]
__global__ __launch_bounds__(256) void wconv(const float* __restrict__ in,
                                             u16* __restrict__ out, int K, int N)
{
  __shared__ float t[32][33];
  const int bk = blockIdx.x*32, bn = blockIdx.y*32;
  const int tn = threadIdx.x & 31, tk = threadIdx.x >> 5; // tk 0..7
  #pragma unroll
  for (int j=0;j<4;++j)
    t[tk+8*j][tn] = in[(size_t)(bk+tk+8*j)*N + bn + tn];
  __syncthreads();
  #pragma unroll
  for (int j=0;j<4;++j)
    out[(size_t)(bn+tk+8*j)*K + bk + tn] = f2bf(t[tn][tk+8*j]);
}

// ---------------- bf16 transpose: in u16 [K][N] -> out u16 [N][K]
__global__ __launch_bounds__(256) void tconv(const u16* __restrict__ in,
                                             u16* __restrict__ out, int K, int N)
{
  __shared__ u16 t[32][34];
  const int bk = blockIdx.x*32, bn = blockIdx.y*32;
  const int tn = threadIdx.x & 31, tk = threadIdx.x >> 5; // tk 0..7
  #pragma unroll
  for (int j=0;j<4;++j)
    t[tk+8*j][tn] = in[(size_t)(bk+tk+8*j)*N + bn + tn];
  __syncthreads();
  #pragma unroll
  for (int j=0;j<4;++j)
    out[(size_t)(bn+tk+8*j)*K + bk + tn] = t[tn][tk+8*j];
}

// ---------------- LayerNorm: fp32 [rows][768] -> bf16 [rows][768], wave per row
__global__ __launch_bounds__(256) void ln_k(const float* __restrict__ in,
    const float* __restrict__ gw, const float* __restrict__ gb,
    u16* __restrict__ out)
{
  const int row = blockIdx.x*4 + (threadIdx.x>>6);
  const int l = threadIdx.x & 63;
  const float* p = in + (size_t)row*HID;
  float4 v[3];
  float s=0.f, ss=0.f;
  #pragma unroll
  for (int j=0;j<3;++j){
    v[j] = *(const float4*)(p + j*256 + l*4);
    s  += v[j].x + v[j].y + v[j].z + v[j].w;
    ss += v[j].x*v[j].x + v[j].y*v[j].y + v[j].z*v[j].z + v[j].w*v[j].w;
  }
  #pragma unroll
  for (int m=1;m<64;m<<=1){
    s  += __shfl_xor(s,  m, 64);
    ss += __shfl_xor(ss, m, 64);
  }
  const float mu = s * (1.f/768.f);
  const float rstd = rsqrtf(ss*(1.f/768.f) - mu*mu + 1e-5f);
  #pragma unroll
  for (int j=0;j<3;++j){
    const float4 wv = *(const float4*)(gw + j*256 + l*4);
    const float4 bv = *(const float4*)(gb + j*256 + l*4);
    ushort4 o;
    o.x = f2bf((v[j].x-mu)*rstd*wv.x + bv.x);
    o.y = f2bf((v[j].y-mu)*rstd*wv.y + bv.y);
    o.z = f2bf((v[j].z-mu)*rstd*wv.z + bv.z);
    o.w = f2bf((v[j].w-mu)*rstd*wv.w + bv.w);
    *(ushort4*)(out + (size_t)row*HID + j*256 + l*4) = o;
  }
}

// ---------------- GEMM: C[M][N] = A[M][K](bf16) * Bt[N][K](bf16)^T + bias, epilogues
// 128x128 tile, BK=32. 3-buffer pipeline with COUNTED vmcnt (T4): per K-step,
// issue stage(t+2), ds_read(t)+MFMA, then s_waitcnt vmcnt(4) (waits only t+1's
// 4 loads; t+2's stay in flight across the barrier) + raw s_barrier.
// Safety: each wave waits its OWN t+1 loads; barrier makes the union complete.
// buf[(t+2)%3] rewrite happens only after the barrier its consumers passed.
template<int MODE>
__global__ __launch_bounds__(256) void gemm_bt(const u16* __restrict__ A,
    const u16* __restrict__ Bt, const float* __restrict__ bias0,
    const float* __restrict__ bias1, const float* __restrict__ bias2,
    const float* __restrict__ res, void* __restrict__ outp,
    int N, int K, long wstride, long ostride)
{
  __shared__ __align__(16) u16 sA[3][128*32];
  __shared__ __align__(16) u16 sB[3][128*32];
  const int tid = threadIdx.x, l = tid&63, w = tid>>6;
  const int wr = w>>1, wc = w&1, hi = l>>4, lo = l&15;
  const int bm = blockIdx.x*128, bn = blockIdx.y*128;
  const int z = blockIdx.z;
  const u16* Bz = Bt + (size_t)z * (size_t)wstride;
  const float* bias = (z==0) ? bias0 : ((z==1)? bias1 : bias2);

  const u16* Arow = A  + (size_t)bm*K;
  const u16* Brow = Bz + (size_t)bn*K;

  const f32x4 zv = {0.f,0.f,0.f,0.f};
  f32x4 acc[4][4];
  #pragma unroll
  for (int i=0;i<4;++i)
    #pragma unroll
    for (int j=0;j<4;++j) acc[i][j] = zv;

  const int r0_ = tid>>2, off_ = (tid&3)*8;      // 64 rows by 256 threads
  const int r1_ = r0_ + 64;

  // 4 loads per stage (A:2, B:2)
  #define STAGE(T, BUF) do { \
    const int kt_ = (T) << 5; \
    gload16(Arow + (size_t)r0_*K + kt_ + off_, (char*)sA[BUF] + tid*16); \
    gload16(Arow + (size_t)r1_*K + kt_ + off_, (char*)sA[BUF] + (tid+256)*16); \
    gload16(Brow + (size_t)r0_*K + kt_ + off_, (char*)sB[BUF] + tid*16); \
    gload16(Brow + (size_t)r1_*K + kt_ + off_, (char*)sB[BUF] + (tid+256)*16); \
  } while(0)

  const int NT = K >> 5;     // >= 24 for all our shapes
  STAGE(0, 0);
  STAGE(1, 1);
  asm volatile("s_waitcnt vmcnt(4)" ::: "memory");   // tile 0 landed
  __builtin_amdgcn_s_barrier();
  __builtin_amdgcn_sched_barrier(0);

  int cur = 0;
  for (int t=0; t<NT; ++t){
    int nb = cur+2; if (nb>=3) nb-=3;
    if (t+2 < NT) STAGE(t+2, nb);
    short8 af[4], bfv[4];
    #pragma unroll
    for (int i=0;i<4;++i){
      af[i]  = *(const short8*)(sA[cur] + (wr*64 + i*16 + lo)*32 + hi*8);
      bfv[i] = *(const short8*)(sB[cur] + (wc*64 + i*16 + lo)*32 + hi*8);
    }
    #pragma unroll
    for (int mi=0;mi<4;++mi)
      #pragma unroll
      for (int ni=0;ni<4;++ni)
        acc[mi][ni] = __builtin_amdgcn_mfma_f32_16x16x32_bf16(af[mi], bfv[ni], acc[mi][ni], 0,0,0);
    if (t+1 < NT){
      if (t+2 < NT) asm volatile("s_waitcnt vmcnt(4)" ::: "memory");  // t+1 landed
      else          asm volatile("s_waitcnt vmcnt(0)" ::: "memory");  // last prefetch
      __builtin_amdgcn_s_barrier();
      __builtin_amdgcn_sched_barrier(0);
    }
    cur = (cur+1==3) ? 0 : cur+1;
  }
  #undef STAGE

  #pragma unroll
  for (int mi=0;mi<4;++mi)
    #pragma unroll
    for (int ni=0;ni<4;++ni){
      const int r0 = bm + wr*64 + mi*16 + 4*hi;
      const int cc = bn + wc*64 + ni*16 + lo;
      const float bv = bias[cc];
      #pragma unroll
      for (int g=0; g<4; ++g){
        const size_t idx = (size_t)(r0+g)*N + cc;
        float v = acc[mi][ni][g] + bv;
        if (MODE == 0){
          ((u16*)outp + (size_t)z*(size_t)ostride)[idx] = f2bf(v);
        } else if (MODE == 1){
          ((float*)outp)[idx] = res[idx] + v;
        } else {
          // gelu (tanh form, overflow-safe)
          float u = v*(0.7978845608f + 0.0356774081f*v*v);
          float e = __expf(2.f*u);
          float th = 1.f - 2.f/(1.f + e);
          ((u16*)outp)[idx] = f2bf(0.5f*v*(1.f + th));
        }
      }
    }
}

// ---------------- causal flash attention, swapped-QK^T, 4 waves x 16 q-rows, BKV=64
// exp2-domain softmax (log2e folded into Q scale), defer-max THR=10,
// P packing via v_cvt_pk_bf16_f32.
__global__ __launch_bounds__(256, 4) void attn_k(const u16* __restrict__ Qm,
                                                 const u16* __restrict__ Km,
                                                 const u16* __restrict__ Vt,
                                                 u16* __restrict__ Om)
{
  __shared__ __align__(16) u16 sK [64*64];   // [kv][d], 16B-granule XOR swizzle
  __shared__ __align__(16) u16 sVT[64*64];   // [d][kv], 16B-granule XOR swizzle
  const int tid = threadIdx.x, l = tid & 63, w = tid >> 6;
  const int hi = l >> 4, lo = l & 15;
  const int idx = blockIdx.x;
  const int qb = 31 - (idx / 48);            // heavy blocks dispatched first
  const int bh = idx % 48;
  const int b = bh / NHEAD, h = bh - (bh / NHEAD) * NHEAD;
  const size_t rb = (size_t)b * SEQ;
  const int qw = qb*64 + w*16;

  // Q fragments (B-operand of QK^T), scale = 0.125 * log2(e) -> exp2-domain scores
  short8 qf[2];
  #pragma unroll
  for (int ks=0; ks<2; ++ks){
    short8 t = *(const short8*)(Qm + (rb + qw + lo)*HID + h*64 + ks*32 + hi*8);
    #pragma unroll
    for (int i=0;i<8;++i) t[i] = (short)f2bf(bf2f((u16)t[i]) * 0.1803368801f);
    qf[ks] = t;
  }

  const f32x4 zv = {0.f,0.f,0.f,0.f};
  f32x4 oa[4] = {zv, zv, zv, zv};            // O^T: lane holds O[q=lo][d=nd*16+4hi+g]
  float m = -INFINITY, lsum = 0.f;
  const int srcA = (((2*hi)  & 3) << 4) | lo;
  const int srcB = (((2*hi+1)& 3) << 4) | lo;

  for (int t=0; t<=qb; ++t){
    const int kv0 = t*64;
    __syncthreads();
    // stage K [64 kv][64 d], source-side XOR swizzle on 16B granules
    #pragma unroll
    for (int j=0;j<2;++j){
      int c = tid + 256*j;
      int row = c >> 3;
      int d0 = ((c&7) ^ (row&7))*8;
      gload16(Km + (rb + kv0 + row)*HID + h*64 + d0, (char*)sK + c*16);
    }
    // stage V^T [64 d][64 kv] from pre-transposed Vt[768][8192], same swizzle
    #pragma unroll
    for (int j=0;j<2;++j){
      int c = tid + 256*j;
      int row = c >> 3;
      int k0 = ((c&7) ^ (row&7))*8;
      gload16(Vt + (size_t)(h*64 + row)*NROWS + rb + kv0 + k0, (char*)sVT + c*16);
    }
    __syncthreads();

    // QK^T (swapped): sc[ni][g] = S^T[k=ni*16+4hi+g][q=lo]  (exp2 domain)
    f32x4 sc[4] = {zv, zv, zv, zv};
    #pragma unroll
    for (int ks=0;ks<2;++ks){
      #pragma unroll
      for (int ni=0;ni<4;++ni){
        short8 kf = *(const short8*)(sK + (ni*16 + lo)*64 + ((ks*32 + hi*8) ^ ((lo&7)*8)));
        sc[ni] = __builtin_amdgcn_mfma_f32_16x16x32_bf16(kf, qf[ks], sc[ni], 0,0,0);
      }
    }

    if (t == qb){  // boundary tile: causal mask (k > q)
      #pragma unroll
      for (int ni=0;ni<4;++ni)
        #pragma unroll
        for (int g=0; g<4; ++g){
          int kg = kv0 + ni*16 + 4*hi + g;
          if (kg > qw + lo) sc[ni][g] = -INFINITY;
        }
    }

    // tile max (tree), then cross-hi reduce
    float a0 = fmaxf(fmaxf(sc[0][0], sc[0][1]), fmaxf(sc[0][2], sc[0][3]));
    float a1 = fmaxf(fmaxf(sc[1][0], sc[1][1]), fmaxf(sc[1][2], sc[1][3]));
    float a2 = fmaxf(fmaxf(sc[2][0], sc[2][1]), fmaxf(sc[2][2], sc[2][3]));
    float a3 = fmaxf(fmaxf(sc[3][0], sc[3][1]), fmaxf(sc[3][2], sc[3][3]));
    float pm = fmaxf(fmaxf(a0, a1), fmaxf(a2, a3));
    pm = fmaxf(pm, __shfl_xor(pm, 16, 64));
    pm = fmaxf(pm, __shfl_xor(pm, 32, 64));

    // defer-max: only rescale when the running max grew by > 10 (P <= 2^10)
    if (!__all(pm - m <= 10.f)){
      const float mnew = fmaxf(m, pm);
      const float alpha = __builtin_amdgcn_exp2f(m - mnew);
      lsum *= alpha;
      #pragma unroll
      for (int nd=0;nd<4;++nd){
        oa[nd][0]*=alpha; oa[nd][1]*=alpha; oa[nd][2]*=alpha; oa[nd][3]*=alpha;
      }
      m = mnew;
    }

    float ps = 0.f;
    #pragma unroll
    for (int ni=0;ni<4;++ni)
      #pragma unroll
      for (int g=0; g<4; ++g){
        float e = __builtin_amdgcn_exp2f(sc[ni][g] - m);
        sc[ni][g] = e;
        ps += e;
      }
    ps += __shfl_xor(ps, 16, 64);
    ps += __shfl_xor(ps, 32, 64);
    lsum += ps;

    // PV: per ks half (k=32ks..32ks+31)
    #pragma unroll
    for (int ks=0;ks<2;++ks){
      // P fragment via shfl: lane (hi,lo) needs P[q=lo][k=32ks+8hi+j], j=0..7
      unsigned pkA0 = cvtpk(sc[2*ks  ][0], sc[2*ks  ][1]);
      unsigned pkA1 = cvtpk(sc[2*ks  ][2], sc[2*ks  ][3]);
      unsigned pkB0 = cvtpk(sc[2*ks+1][0], sc[2*ks+1][1]);
      unsigned pkB1 = cvtpk(sc[2*ks+1][2], sc[2*ks+1][3]);
      unsigned a0u = (unsigned)__shfl((int)pkA0, srcA, 64);
      unsigned b0u = (unsigned)__shfl((int)pkB0, srcA, 64);
      unsigned a1u = (unsigned)__shfl((int)pkA1, srcA, 64);
      unsigned b1u = (unsigned)__shfl((int)pkB1, srcA, 64);
      unsigned a2u = (unsigned)__shfl((int)pkA0, srcB, 64);
      unsigned b2u = (unsigned)__shfl((int)pkB0, srcB, 64);
      unsigned a3u = (unsigned)__shfl((int)pkA1, srcB, 64);
      unsigned b3u = (unsigned)__shfl((int)pkB1, srcB, 64);
      union { u32x4 u; short8 s; } pf;
      pf.u = (u32x4){ (hi<2)?a0u:b0u, (hi<2)?a1u:b1u, (hi<2)?a2u:b2u, (hi<2)?a3u:b3u };

      #pragma unroll
      for (int nd=0;nd<4;++nd){
        short8 vf = *(const short8*)(sVT + (nd*16 + lo)*64 + ((ks*32 + hi*8) ^ ((lo&7)*8)));
        oa[nd] = __builtin_amdgcn_mfma_f32_16x16x32_bf16(vf, pf.s, oa[nd], 0,0,0);
      }
    }
  }

  // epilogue: O[q=lo][d] = oa / lsum ; d = nd*16+4hi+g contiguous in g
  const float inv = 1.f / lsum;
  #pragma unroll
  for (int nd=0;nd<4;++nd){
    ushort4 o;
    o.x = f2bf(oa[nd][0]*inv);
    o.y = f2bf(oa[nd][1]*inv);
    o.z = f2bf(oa[nd][2]*inv);
    o.w = f2bf(oa[nd][3]*inv);
    *(ushort4*)(Om + (rb + qw + lo)*HID + h*64 + nd*16 + 4*hi) = o;
  }
}

extern "C" void kernel_launch(void* const* d_in, const int* in_sizes, int n_in,
                              void* d_out, int out_size, void* d_ws, size_t ws_size,
                              hipStream_t stream)
{
  const float* x    = (const float*)d_in[0];
  const float* ln1w = (const float*)d_in[1];
  const float* ln1b = (const float*)d_in[2];
  const float* Wq   = (const float*)d_in[3];
  const float* bq   = (const float*)d_in[4];
  const float* Wk   = (const float*)d_in[5];
  const float* bk   = (const float*)d_in[6];
  const float* Wv   = (const float*)d_in[7];
  const float* bv   = (const float*)d_in[8];
  const float* Wo   = (const float*)d_in[9];
  const float* bo   = (const float*)d_in[10];
  const float* ln2w = (const float*)d_in[11];
  const float* ln2b = (const float*)d_in[12];
  const float* W1   = (const float*)d_in[13];
  const float* b1   = (const float*)d_in[14];
  const float* W2   = (const float*)d_in[15];
  const float* b2   = (const float*)d_in[16];

  // workspace layout (bf16 elements unless noted)
  u16* wq_t = (u16*)d_ws;                 // [768][768]
  u16* wk_t = wq_t + 589824;
  u16* wv_t = wk_t + 589824;
  u16* wo_t = wv_t + 589824;
  u16* w1_t = wo_t + 589824;              // [3072][768]
  u16* w2_t = w1_t + 2359296;             // [768][3072]
  u16* hbf  = w2_t + 2359296;             // LN out [8192][768]; reused as V^T [768][8192]
  u16* qb_  = hbf + 6291456;              // Q [8192][768]
  u16* kb_  = qb_ + 6291456;
  u16* vb_  = kb_ + 6291456;
  u16* atb  = vb_ + 6291456;              // attn out [8192][768]
  u16* ub   = qb_;                        // MLP hidden [8192][3072], reuses Q/K/V/attn
  float* x2 = (float*)(atb + 6291456);    // fp32 [8192][768]

  const size_t need = 102236160ull;
  if (ws_size < need) return;

  dim3 blk(256);
  wconv<<<dim3(24,24), blk, 0, stream>>>(Wq, wq_t, 768, 768);
  wconv<<<dim3(24,24), blk, 0, stream>>>(Wk, wk_t, 768, 768);
  wconv<<<dim3(24,24), blk, 0, stream>>>(Wv, wv_t, 768, 768);
  wconv<<<dim3(24,24), blk, 0, stream>>>(Wo, wo_t, 768, 768);
  wconv<<<dim3(24,96), blk, 0, stream>>>(W1, w1_t, 768, 3072);
  wconv<<<dim3(96,24), blk, 0, stream>>>(W2, w2_t, 3072, 768);

  ln_k<<<2048, blk, 0, stream>>>(x, ln1w, ln1b, hbf);

  // fused QKV: z selects Wq/Wk/Wv and Q/K/V out (z=2 lands in vb_)
  gemm_bt<0><<<dim3(64,6,3), blk, 0, stream>>>(hbf, wq_t, bq, bk, bv,
      nullptr, (void*)qb_, 768, 768, 589824L, 6291456L);
  tconv<<<dim3(256,24), blk, 0, stream>>>(vb_, hbf, 8192, 768);

  attn_k<<<dim3(1536), blk, 0, stream>>>(qb_, kb_, hbf, atb);

  // x2 = x + attn@Wo + bo
  gemm_bt<1><<<dim3(64,6,1), blk, 0, stream>>>(atb, wo_t, bo, bo, bo,
      x, (void*)x2, 768, 768, 0L, 0L);

  ln_k<<<2048, blk, 0, stream>>>(x2, ln2w, ln2b, hbf);

  // u = gelu(h2@W1 + b1)
  gemm_bt<2><<<dim3(64,24,1), blk, 0, stream>>>(hbf, w1_t, b1, b1, b1,
      nullptr, (void*)ub, 3072, 768, 0L, 0L);

  // out = x2 + u@W2 + b2
  gemm_bt<1><<<dim3(64,6,1), blk, 0, stream>>>(ub, w2_t, b2, b2, b2,
      x2, d_out, 768, 3072, 0L, 0L);
}

// Round 11
// 380.435 us; speedup vs baseline: 1.0637x; 1.0637x over previous
//
#include <hip/hip_runtime.h>
#include <cmath>
#include <stdint.h>

typedef unsigned short u16;
typedef __attribute__((ext_vector_type(8))) short short8;
typedef __attribute__((ext_vector_type(4))) float f32x4;
typedef __attribute__((ext_vector_type(4))) unsigned int u32x4;

#define HID 768
#define FF  3072
#define SEQ 2048
#define NHEAD 12
#define NROWS 8192   // B*S

__device__ __forceinline__ float bf2f(u16 u){ return __uint_as_float(((unsigned)u)<<16); }
__device__ __forceinline__ u16 f2bf(float f){
  unsigned x = __float_as_uint(f);
  x += 0x7fffu + ((x>>16)&1u);
  return (u16)(x>>16);
}
__device__ __forceinline__ unsigned cvtpk(float a, float b){   // lo=bf16(a), hi=bf16(b)
  unsigned r;
  asm("v_cvt_pk_bf16_f32 %0, %1, %2" : "=v"(r) : "v"(a), "v"(b));
  return r;
}
__device__ __forceinline__ void gload16(const void* g, void* l){
  __builtin_amdgcn_global_load_lds((const __attribute__((address_space(1))) unsigned*)g,
                                   (__attribute__((address_space(3))) unsigned*)l, 16, 0, 0);
}

// ---------------- weight convert + transpose: in fp32 [K][N] -> out bf16 [N][K]
__global__ __launch_bounds__(256) void wconv(const float* __restrict__ in,
                                             u16* __restrict__ out, int K, int N)
{
  __shared__ float t[32][33];
  const int bk = blockIdx.x*32, bn = blockIdx.y*32;
  const int tn = threadIdx.x & 31, tk = threadIdx.x >> 5; // tk 0..7
  #pragma unroll
  for (int j=0;j<4;++j)
    t[tk+8*j][tn] = in[(size_t)(bk+tk+8*j)*N + bn + tn];
  __syncthreads();
  #pragma unroll
  for (int j=0;j<4;++j)
    out[(size_t)(bn+tk+8*j)*K + bk + tn] = f2bf(t[tn][tk+8*j]);
}

// ---------------- bf16 transpose: in u16 [K][N] -> out u16 [N][K]
__global__ __launch_bounds__(256) void tconv(const u16* __restrict__ in,
                                             u16* __restrict__ out, int K, int N)
{
  __shared__ u16 t[32][34];
  const int bk = blockIdx.x*32, bn = blockIdx.y*32;
  const int tn = threadIdx.x & 31, tk = threadIdx.x >> 5; // tk 0..7
  #pragma unroll
  for (int j=0;j<4;++j)
    t[tk+8*j][tn] = in[(size_t)(bk+tk+8*j)*N + bn + tn];
  __syncthreads();
  #pragma unroll
  for (int j=0;j<4;++j)
    out[(size_t)(bn+tk+8*j)*K + bk + tn] = t[tn][tk+8*j];
}

// ---------------- LayerNorm: fp32 [rows][768] -> bf16 [rows][768], wave per row
__global__ __launch_bounds__(256) void ln_k(const float* __restrict__ in,
    const float* __restrict__ gw, const float* __restrict__ gb,
    u16* __restrict__ out)
{
  const int row = blockIdx.x*4 + (threadIdx.x>>6);
  const int l = threadIdx.x & 63;
  const float* p = in + (size_t)row*HID;
  float4 v[3];
  float s=0.f, ss=0.f;
  #pragma unroll
  for (int j=0;j<3;++j){
    v[j] = *(const float4*)(p + j*256 + l*4);
    s  += v[j].x + v[j].y + v[j].z + v[j].w;
    ss += v[j].x*v[j].x + v[j].y*v[j].y + v[j].z*v[j].z + v[j].w*v[j].w;
  }
  #pragma unroll
  for (int m=1;m<64;m<<=1){
    s  += __shfl_xor(s,  m, 64);
    ss += __shfl_xor(ss, m, 64);
  }
  const float mu = s * (1.f/768.f);
  const float rstd = rsqrtf(ss*(1.f/768.f) - mu*mu + 1e-5f);
  #pragma unroll
  for (int j=0;j<3;++j){
    const float4 wv = *(const float4*)(gw + j*256 + l*4);
    const float4 bv = *(const float4*)(gb + j*256 + l*4);
    ushort4 o;
    o.x = f2bf((v[j].x-mu)*rstd*wv.x + bv.x);
    o.y = f2bf((v[j].y-mu)*rstd*wv.y + bv.y);
    o.z = f2bf((v[j].z-mu)*rstd*wv.z + bv.z);
    o.w = f2bf((v[j].w-mu)*rstd*wv.w + bv.w);
    *(ushort4*)(out + (size_t)row*HID + j*256 + l*4) = o;
  }
}

// ---------------- GEMM: C[M][N] = A[M][K](bf16) * Bt[N][K](bf16)^T + bias, epilogues
// R8-verified structure: 128x128 tile, BK=32, 2-phase double-buffer, stage(t+1)
// issued BEFORE compute(t), ONE __syncthreads per K-step (compiler-scheduled
// waitcnts — do NOT pin with sched_barrier, m141 trap).
template<int MODE>
__global__ __launch_bounds__(256) void gemm_bt(const u16* __restrict__ A,
    const u16* __restrict__ Bt, const float* __restrict__ bias0,
    const float* __restrict__ bias1, const float* __restrict__ bias2,
    const float* __restrict__ res, void* __restrict__ outp,
    int N, int K, long wstride, long ostride)
{
  __shared__ __align__(16) u16 sA[2][128*32];
  __shared__ __align__(16) u16 sB[2][128*32];
  const int tid = threadIdx.x, l = tid&63, w = tid>>6;
  const int wr = w>>1, wc = w&1, hi = l>>4, lo = l&15;
  const int bm = blockIdx.x*128, bn = blockIdx.y*128;
  const int z = blockIdx.z;
  const u16* Bz = Bt + (size_t)z * (size_t)wstride;
  const float* bias = (z==0) ? bias0 : ((z==1)? bias1 : bias2);

  const u16* Arow = A  + (size_t)bm*K;
  const u16* Brow = Bz + (size_t)bn*K;

  const f32x4 zv = {0.f,0.f,0.f,0.f};
  f32x4 acc[4][4];
  #pragma unroll
  for (int i=0;i<4;++i)
    #pragma unroll
    for (int j=0;j<4;++j) acc[i][j] = zv;

  const int r0_ = tid>>2, off_ = (tid&3)*8;        // 64 rows by 256 threads
  const int r1_ = r0_ + 64;

  // prologue: stage tile 0 into buf 0
  gload16(Arow + (size_t)r0_*K + off_, (char*)sA[0] + tid*16);
  gload16(Arow + (size_t)r1_*K + off_, (char*)sA[0] + (tid+256)*16);
  gload16(Brow + (size_t)r0_*K + off_, (char*)sB[0] + tid*16);
  gload16(Brow + (size_t)r1_*K + off_, (char*)sB[0] + (tid+256)*16);
  __syncthreads();

  const int NT = K >> 5;
  int cur = 0;
  for (int t=0; t<NT; ++t){
    if (t+1 < NT){
      const int kt = (t+1) << 5;
      gload16(Arow + (size_t)r0_*K + kt + off_, (char*)sA[cur^1] + tid*16);
      gload16(Arow + (size_t)r1_*K + kt + off_, (char*)sA[cur^1] + (tid+256)*16);
      gload16(Brow + (size_t)r0_*K + kt + off_, (char*)sB[cur^1] + tid*16);
      gload16(Brow + (size_t)r1_*K + kt + off_, (char*)sB[cur^1] + (tid+256)*16);
    }
    short8 af[4], bfv[4];
    #pragma unroll
    for (int i=0;i<4;++i){
      af[i]  = *(const short8*)(sA[cur] + (wr*64 + i*16 + lo)*32 + hi*8);
      bfv[i] = *(const short8*)(sB[cur] + (wc*64 + i*16 + lo)*32 + hi*8);
    }
    #pragma unroll
    for (int mi=0;mi<4;++mi)
      #pragma unroll
      for (int ni=0;ni<4;++ni)
        acc[mi][ni] = __builtin_amdgcn_mfma_f32_16x16x32_bf16(af[mi], bfv[ni], acc[mi][ni], 0,0,0);
    __syncthreads();   // vmcnt(0)+lgkm drain lands here: after MFMA
    cur ^= 1;
  }

  #pragma unroll
  for (int mi=0;mi<4;++mi)
    #pragma unroll
    for (int ni=0;ni<4;++ni){
      const int r0 = bm + wr*64 + mi*16 + 4*hi;
      const int cc = bn + wc*64 + ni*16 + lo;
      const float bv = bias[cc];
      #pragma unroll
      for (int g=0; g<4; ++g){
        const size_t idx = (size_t)(r0+g)*N + cc;
        float v = acc[mi][ni][g] + bv;
        if (MODE == 0){
          ((u16*)outp + (size_t)z*(size_t)ostride)[idx] = f2bf(v);
        } else if (MODE == 1){
          ((float*)outp)[idx] = res[idx] + v;
        } else {
          // gelu (tanh form, overflow-safe)
          float u = v*(0.7978845608f + 0.0356774081f*v*v);
          float e = __expf(2.f*u);
          float th = 1.f - 2.f/(1.f + e);
          ((u16*)outp)[idx] = f2bf(0.5f*v*(1.f + th));
        }
      }
    }
}

// ---------------- causal flash attention, swapped-QK^T, 4 waves x 16 q-rows, BKV=64
// exp2-domain softmax (log2e folded into Q scale), defer-max THR=10,
// P packing via v_cvt_pk_bf16_f32. (R9-verified)
__global__ __launch_bounds__(256, 4) void attn_k(const u16* __restrict__ Qm,
                                                 const u16* __restrict__ Km,
                                                 const u16* __restrict__ Vt,
                                                 u16* __restrict__ Om)
{
  __shared__ __align__(16) u16 sK [64*64];   // [kv][d], 16B-granule XOR swizzle
  __shared__ __align__(16) u16 sVT[64*64];   // [d][kv], 16B-granule XOR swizzle
  const int tid = threadIdx.x, l = tid & 63, w = tid >> 6;
  const int hi = l >> 4, lo = l & 15;
  const int idx = blockIdx.x;
  const int qb = 31 - (idx / 48);            // heavy blocks dispatched first
  const int bh = idx % 48;
  const int b = bh / NHEAD, h = bh - (bh / NHEAD) * NHEAD;
  const size_t rb = (size_t)b * SEQ;
  const int qw = qb*64 + w*16;

  // Q fragments (B-operand of QK^T), scale = 0.125 * log2(e) -> exp2-domain scores
  short8 qf[2];
  #pragma unroll
  for (int ks=0; ks<2; ++ks){
    short8 t = *(const short8*)(Qm + (rb + qw + lo)*HID + h*64 + ks*32 + hi*8);
    #pragma unroll
    for (int i=0;i<8;++i) t[i] = (short)f2bf(bf2f((u16)t[i]) * 0.1803368801f);
    qf[ks] = t;
  }

  const f32x4 zv = {0.f,0.f,0.f,0.f};
  f32x4 oa[4] = {zv, zv, zv, zv};            // O^T: lane holds O[q=lo][d=nd*16+4hi+g]
  float m = -INFINITY, lsum = 0.f;
  const int srcA = (((2*hi)  & 3) << 4) | lo;
  const int srcB = (((2*hi+1)& 3) << 4) | lo;

  for (int t=0; t<=qb; ++t){
    const int kv0 = t*64;
    __syncthreads();
    // stage K [64 kv][64 d], source-side XOR swizzle on 16B granules
    #pragma unroll
    for (int j=0;j<2;++j){
      int c = tid + 256*j;
      int row = c >> 3;
      int d0 = ((c&7) ^ (row&7))*8;
      gload16(Km + (rb + kv0 + row)*HID + h*64 + d0, (char*)sK + c*16);
    }
    // stage V^T [64 d][64 kv] from pre-transposed Vt[768][8192], same swizzle
    #pragma unroll
    for (int j=0;j<2;++j){
      int c = tid + 256*j;
      int row = c >> 3;
      int k0 = ((c&7) ^ (row&7))*8;
      gload16(Vt + (size_t)(h*64 + row)*NROWS + rb + kv0 + k0, (char*)sVT + c*16);
    }
    __syncthreads();

    // QK^T (swapped): sc[ni][g] = S^T[k=ni*16+4hi+g][q=lo]  (exp2 domain)
    f32x4 sc[4] = {zv, zv, zv, zv};
    #pragma unroll
    for (int ks=0;ks<2;++ks){
      #pragma unroll
      for (int ni=0;ni<4;++ni){
        short8 kf = *(const short8*)(sK + (ni*16 + lo)*64 + ((ks*32 + hi*8) ^ ((lo&7)*8)));
        sc[ni] = __builtin_amdgcn_mfma_f32_16x16x32_bf16(kf, qf[ks], sc[ni], 0,0,0);
      }
    }

    if (t == qb){  // boundary tile: causal mask (k > q)
      #pragma unroll
      for (int ni=0;ni<4;++ni)
        #pragma unroll
        for (int g=0; g<4; ++g){
          int kg = kv0 + ni*16 + 4*hi + g;
          if (kg > qw + lo) sc[ni][g] = -INFINITY;
        }
    }

    // tile max (tree), then cross-hi reduce
    float a0 = fmaxf(fmaxf(sc[0][0], sc[0][1]), fmaxf(sc[0][2], sc[0][3]));
    float a1 = fmaxf(fmaxf(sc[1][0], sc[1][1]), fmaxf(sc[1][2], sc[1][3]));
    float a2 = fmaxf(fmaxf(sc[2][0], sc[2][1]), fmaxf(sc[2][2], sc[2][3]));
    float a3 = fmaxf(fmaxf(sc[3][0], sc[3][1]), fmaxf(sc[3][2], sc[3][3]));
    float pm = fmaxf(fmaxf(a0, a1), fmaxf(a2, a3));
    pm = fmaxf(pm, __shfl_xor(pm, 16, 64));
    pm = fmaxf(pm, __shfl_xor(pm, 32, 64));

    // defer-max: only rescale when the running max grew by > 10 (P <= 2^10)
    if (!__all(pm - m <= 10.f)){
      const float mnew = fmaxf(m, pm);
      const float alpha = __builtin_amdgcn_exp2f(m - mnew);
      lsum *= alpha;
      #pragma unroll
      for (int nd=0;nd<4;++nd){
        oa[nd][0]*=alpha; oa[nd][1]*=alpha; oa[nd][2]*=alpha; oa[nd][3]*=alpha;
      }
      m = mnew;
    }

    float ps = 0.f;
    #pragma unroll
    for (int ni=0;ni<4;++ni)
      #pragma unroll
      for (int g=0; g<4; ++g){
        float e = __builtin_amdgcn_exp2f(sc[ni][g] - m);
        sc[ni][g] = e;
        ps += e;
      }
    ps += __shfl_xor(ps, 16, 64);
    ps += __shfl_xor(ps, 32, 64);
    lsum += ps;

    // PV: per ks half (k=32ks..32ks+31)
    #pragma unroll
    for (int ks=0;ks<2;++ks){
      // P fragment via shfl: lane (hi,lo) needs P[q=lo][k=32ks+8hi+j], j=0..7
      unsigned pkA0 = cvtpk(sc[2*ks  ][0], sc[2*ks  ][1]);
      unsigned pkA1 = cvtpk(sc[2*ks  ][2], sc[2*ks  ][3]);
      unsigned pkB0 = cvtpk(sc[2*ks+1][0], sc[2*ks+1][1]);
      unsigned pkB1 = cvtpk(sc[2*ks+1][2], sc[2*ks+1][3]);
      unsigned a0u = (unsigned)__shfl((int)pkA0, srcA, 64);
      unsigned b0u = (unsigned)__shfl((int)pkB0, srcA, 64);
      unsigned a1u = (unsigned)__shfl((int)pkA1, srcA, 64);
      unsigned b1u = (unsigned)__shfl((int)pkB1, srcA, 64);
      unsigned a2u = (unsigned)__shfl((int)pkA0, srcB, 64);
      unsigned b2u = (unsigned)__shfl((int)pkB0, srcB, 64);
      unsigned a3u = (unsigned)__shfl((int)pkA1, srcB, 64);
      unsigned b3u = (unsigned)__shfl((int)pkB1, srcB, 64);
      union { u32x4 u; short8 s; } pf;
      pf.u = (u32x4){ (hi<2)?a0u:b0u, (hi<2)?a1u:b1u, (hi<2)?a2u:b2u, (hi<2)?a3u:b3u };

      #pragma unroll
      for (int nd=0;nd<4;++nd){
        short8 vf = *(const short8*)(sVT + (nd*16 + lo)*64 + ((ks*32 + hi*8) ^ ((lo&7)*8)));
        oa[nd] = __builtin_amdgcn_mfma_f32_16x16x32_bf16(vf, pf.s, oa[nd], 0,0,0);
      }
    }
  }

  // epilogue: O[q=lo][d] = oa / lsum ; d = nd*16+4hi+g contiguous in g
  const float inv = 1.f / lsum;
  #pragma unroll
  for (int nd=0;nd<4;++nd){
    ushort4 o;
    o.x = f2bf(oa[nd][0]*inv);
    o.y = f2bf(oa[nd][1]*inv);
    o.z = f2bf(oa[nd][2]*inv);
    o.w = f2bf(oa[nd][3]*inv);
    *(ushort4*)(Om + (rb + qw + lo)*HID + h*64 + nd*16 + 4*hi) = o;
  }
}

extern "C" void kernel_launch(void* const* d_in, const int* in_sizes, int n_in,
                              void* d_out, int out_size, void* d_ws, size_t ws_size,
                              hipStream_t stream)
{
  const float* x    = (const float*)d_in[0];
  const float* ln1w = (const float*)d_in[1];
  const float* ln1b = (const float*)d_in[2];
  const float* Wq   = (const float*)d_in[3];
  const float* bq   = (const float*)d_in[4];
  const float* Wk   = (const float*)d_in[5];
  const float* bk   = (const float*)d_in[6];
  const float* Wv   = (const float*)d_in[7];
  const float* bv   = (const float*)d_in[8];
  const float* Wo   = (const float*)d_in[9];
  const float* bo   = (const float*)d_in[10];
  const float* ln2w = (const float*)d_in[11];
  const float* ln2b = (const float*)d_in[12];
  const float* W1   = (const float*)d_in[13];
  const float* b1   = (const float*)d_in[14];
  const float* W2   = (const float*)d_in[15];
  const float* b2   = (const float*)d_in[16];

  // workspace layout (bf16 elements unless noted)
  u16* wq_t = (u16*)d_ws;                 // [768][768]
  u16* wk_t = wq_t + 589824;
  u16* wv_t = wk_t + 589824;
  u16* wo_t = wv_t + 589824;
  u16* w1_t = wo_t + 589824;              // [3072][768]
  u16* w2_t = w1_t + 2359296;             // [768][3072]
  u16* hbf  = w2_t + 2359296;             // LN out [8192][768]; reused as V^T [768][8192]
  u16* qb_  = hbf + 6291456;              // Q [8192][768]
  u16* kb_  = qb_ + 6291456;
  u16* vb_  = kb_ + 6291456;
  u16* atb  = vb_ + 6291456;              // attn out [8192][768]
  u16* ub   = qb_;                        // MLP hidden [8192][3072], reuses Q/K/V/attn
  float* x2 = (float*)(atb + 6291456);    // fp32 [8192][768]

  const size_t need = 102236160ull;
  if (ws_size < need) return;

  dim3 blk(256);
  wconv<<<dim3(24,24), blk, 0, stream>>>(Wq, wq_t, 768, 768);
  wconv<<<dim3(24,24), blk, 0, stream>>>(Wk, wk_t, 768, 768);
  wconv<<<dim3(24,24), blk, 0, stream>>>(Wv, wv_t, 768, 768);
  wconv<<<dim3(24,24), blk, 0, stream>>>(Wo, wo_t, 768, 768);
  wconv<<<dim3(24,96), blk, 0, stream>>>(W1, w1_t, 768, 3072);
  wconv<<<dim3(96,24), blk, 0, stream>>>(W2, w2_t, 3072, 768);

  ln_k<<<2048, blk, 0, stream>>>(x, ln1w, ln1b, hbf);

  // fused QKV: z selects Wq/Wk/Wv and Q/K/V out (z=2 lands in vb_)
  gemm_bt<0><<<dim3(64,6,3), blk, 0, stream>>>(hbf, wq_t, bq, bk, bv,
      nullptr, (void*)qb_, 768, 768, 589824L, 6291456L);
  tconv<<<dim3(256,24), blk, 0, stream>>>(vb_, hbf, 8192, 768);

  attn_k<<<dim3(1536), blk, 0, stream>>>(qb_, kb_, hbf, atb);

  // x2 = x + attn@Wo + bo
  gemm_bt<1><<<dim3(64,6,1), blk, 0, stream>>>(atb, wo_t, bo, bo, bo,
      x, (void*)x2, 768, 768, 0L, 0L);

  ln_k<<<2048, blk, 0, stream>>>(x2, ln2w, ln2b, hbf);

  // u = gelu(h2@W1 + b1)
  gemm_bt<2><<<dim3(64,24,1), blk, 0, stream>>>(hbf, w1_t, b1, b1, b1,
      nullptr, (void*)ub, 3072, 768, 0L, 0L);

  // out = x2 + u@W2 + b2
  gemm_bt<1><<<dim3(64,6,1), blk, 0, stream>>>(ub, w2_t, b2, b2, b2,
      x2, d_out, 768, 3072, 0L, 0L);
}